// Round 3
// baseline (368.309 us; speedup 1.0000x reference)
//
#include <hip/hip_runtime.h>
#include <hip/hip_bf16.h>

#define B_  16
#define CI_ 32
#define H_  224
#define W_  224
#define CO_ 32
#define OH_ 222
#define OW_ 222
#define HW_ (H_*W_)   // 50176
#define K_  288       // CI_*9

#define OHB   4               // output rows per block
#define XROWS (OHB + 2)       // staged input rows (kh halo)
#define XCOLS 66              // 64 outputs + 2 halo cols
#define CISTR 40              // padded ci stride (bf16): 80B, 16B-aligned

typedef __attribute__((ext_vector_type(8))) short short8;   // 8 bf16 = 4 VGPRs
typedef __attribute__((ext_vector_type(4))) float float4v;  // MFMA C/D

// Permute+convert weights once per launch:
// wbf[co*288 + (kh*3+kw)*32 + ci] = bf16(w[co][ci][kh][kw])
__global__ void wprep(const float* __restrict__ w, unsigned short* __restrict__ wbf) {
    int idx = blockIdx.x * 256 + threadIdx.x;
    if (idx >= CO_ * K_) return;
    int co  = idx / K_;
    int rem = idx - co * K_;
    int ci  = rem / 9;
    int g   = rem - ci * 9;           // kh*3+kw
    // RNE f32->bf16
    unsigned int u = __float_as_uint(w[idx]);
    u = u + 0x7FFFu + ((u >> 16) & 1u);
    wbf[co * K_ + g * 32 + ci] = (unsigned short)(u >> 16);
}

// Implicit GEMM, 16x16x32 bf16 MFMA (layouts verified in R2).
// Block: 4 oh-rows x 64 ow x 32 co. Wave wv owns output row oh0+wv:
// 4 ow-subtiles x 2 co-halves = 8 accumulators, 72 MFMA per wave.
// A-frag: m=lane&15 (pixel), k=quad*8+j  <- ds_read_b128 from Xs[row][col][ci]
// B-frag: n=lane&15 (co),    k=quad*8+j  <- global 16B (L1-hot, 18KB total)
// C/D:    col(n)=lane&15, row(m)=quad*4+reg
__global__ __launch_bounds__(256) void conv_mfma(
    const float* __restrict__ x, const unsigned short* __restrict__ wbf,
    const float* __restrict__ bias, float* __restrict__ out)
{
    __shared__ unsigned short Xs[XROWS * XCOLS * CISTR];   // 31680 B

    const int t    = threadIdx.x;
    const int lane = t & 63;
    const int wv   = t >> 6;
    const int ow0  = blockIdx.x * 64;
    const int oh0  = blockIdx.y * OHB;
    const int b    = blockIdx.z;

    // ---------- fill Xs[r][col][ci] = bf16(x[b][ci][oh0+r][ow0+col]) ----------
    // thread t: col = t&63 (wave-coalesced 256B/instr), ci-group = t>>6 (8 ci).
    {
        const int col = t & 63;
        const int ci0 = (t >> 6) * 8;
        const float* xb = x + (size_t)b * CI_ * HW_;
#pragma unroll
        for (int r = 0; r < XROWS; ++r) {
            const int row = oh0 + r;
            const bool rv = row < H_;
            const float* base = xb + (size_t)row * W_ + ow0;
            // main cols 0..63
            {
                const bool v = rv && (ow0 + col) < W_;
                float f[8];
#pragma unroll
                for (int i = 0; i < 8; ++i)
                    f[i] = v ? base[(size_t)(ci0 + i) * HW_ + col] : 0.0f;
                union { short8 s8; __hip_bfloat162 h2[4]; } u;
#pragma unroll
                for (int i = 0; i < 4; ++i)
                    u.h2[i] = __float22bfloat162_rn(make_float2(f[2*i], f[2*i+1]));
                *(short8*)&Xs[(r * XCOLS + col) * CISTR + ci0] = u.s8;
            }
            // halo cols 64,65
            if (col < 2) {
                const int c2 = 64 + col;
                const bool v = rv && (ow0 + c2) < W_;
                float f[8];
#pragma unroll
                for (int i = 0; i < 8; ++i)
                    f[i] = v ? base[(size_t)(ci0 + i) * HW_ + c2] : 0.0f;
                union { short8 s8; __hip_bfloat162 h2[4]; } u;
#pragma unroll
                for (int i = 0; i < 4; ++i)
                    u.h2[i] = __float22bfloat162_rn(make_float2(f[2*i], f[2*i+1]));
                *(short8*)&Xs[(r * XCOLS + c2) * CISTR + ci0] = u.s8;
            }
        }
    }
    __syncthreads();

    // ---------- K-loop: 9 (kh,kw) groups x 32 ci ----------
    const int i16  = lane & 15;
    const int quad = lane >> 4;

    float4v acc[4][2] = {};

    const unsigned short* wr0 = wbf + (size_t)i16 * K_;          // co = i16
    const unsigned short* wr1 = wbf + (size_t)(16 + i16) * K_;   // co = 16+i16

#pragma unroll
    for (int g = 0; g < 9; ++g) {
        const int kh = g / 3;
        const int kw = g - kh * 3;
        const short8 b0 = *(const short8*)&wr0[g * 32 + quad * 8];
        const short8 b1 = *(const short8*)&wr1[g * 32 + quad * 8];
#pragma unroll
        for (int ot = 0; ot < 4; ++ot) {
            const short8 a = *(const short8*)
                &Xs[((wv + kh) * XCOLS + ot * 16 + i16 + kw) * CISTR + quad * 8];
            acc[ot][0] = __builtin_amdgcn_mfma_f32_16x16x32_bf16(a, b0, acc[ot][0], 0, 0, 0);
            acc[ot][1] = __builtin_amdgcn_mfma_f32_16x16x32_bf16(a, b1, acc[ot][1], 0, 0, 0);
        }
    }

    // ---------- epilogue ----------
    const int oh = oh0 + wv;
    if (oh >= OH_) return;
    const float bv0 = bias[i16];
    const float bv1 = bias[16 + i16];
    const size_t o0 = ((size_t)(b * CO_ + i16) * OH_ + oh) * (size_t)OW_;
    const size_t o1 = ((size_t)(b * CO_ + 16 + i16) * OH_ + oh) * (size_t)OW_;
#pragma unroll
    for (int ot = 0; ot < 4; ++ot) {
        const int owb = ow0 + ot * 16 + quad * 4;
#pragma unroll
        for (int r = 0; r < 4; ++r) {
            const int ow = owb + r;
            if (ow < OW_) {
                out[o0 + ow] = acc[ot][0][r] + bv0;
                out[o1 + ow] = acc[ot][1][r] + bv1;
            }
        }
    }
}

extern "C" void kernel_launch(void* const* d_in, const int* in_sizes, int n_in,
                              void* d_out, int out_size, void* d_ws, size_t ws_size,
                              hipStream_t stream) {
    const float* x    = (const float*)d_in[0];
    const float* w    = (const float*)d_in[1];
    const float* bias = (const float*)d_in[2];
    float* out        = (float*)d_out;
    unsigned short* wbf = (unsigned short*)d_ws;   // 9216 bf16 = 18432 B

    wprep<<<(CO_ * K_ + 255) / 256, 256, 0, stream>>>(w, wbf);

    dim3 grid((OW_ + 63) / 64, (OH_ + OHB - 1) / OHB, B_);   // 4 x 56 x 16
    conv_mfma<<<grid, 256, 0, stream>>>(x, wbf, bias, out);
}

// Round 4
// 272.174 us; speedup vs baseline: 1.3532x; 1.3532x over previous
//
#include <hip/hip_runtime.h>
#include <hip/hip_bf16.h>

#define B_  16
#define CI_ 32
#define H_  224
#define W_  224
#define CO_ 32
#define OH_ 222
#define OW_ 222
#define HW_ (H_*W_)      // 50176
#define K_  288          // CI_*9
#define ROWSTR (W_*CI_)  // 7168 elements per xT row

#define XT_OFF   32768                                  // xT offset in d_ws (wbf first)
#define XT_BYTES ((size_t)B_ * HW_ * CI_ * 2)           // 51,380,224 B

typedef __attribute__((ext_vector_type(8))) short short8;   // 8 bf16 = 16B
typedef __attribute__((ext_vector_type(4))) float float4v;  // MFMA C/D
typedef float float4u __attribute__((ext_vector_type(4), aligned(4)));  // unaligned-ok store

// ---------------- weights: w[co][ci][kh][kw] fp32 -> wbf[co][g][ci] bf16 ----------------
__global__ void wprep(const float* __restrict__ w, unsigned short* __restrict__ wbf) {
    int idx = blockIdx.x * 256 + threadIdx.x;
    if (idx >= CO_ * K_) return;
    int co  = idx / K_;
    int rem = idx - co * K_;
    int ci  = rem / 9;
    int g   = rem - ci * 9;           // kh*3+kw
    unsigned int u = __float_as_uint(w[idx]);
    u = u + 0x7FFFu + ((u >> 16) & 1u);
    wbf[co * K_ + g * 32 + ci] = (unsigned short)(u >> 16);
}

// ---------------- x: NCHW fp32 -> NHWC bf16 (one BW-pure pass) ----------------
// thread = one (b,pixel): 32 per-instr-coalesced loads (32 outstanding = good MLP),
// one dense 64B write.
__global__ __launch_bounds__(256) void xform(const float* __restrict__ x,
                                             unsigned short* __restrict__ xT) {
    const int pix = blockIdx.x * 256 + threadIdx.x;   // 0..50175 (196*256 exact)
    const int b   = blockIdx.y;
    const float* xp = x + (size_t)b * CI_ * HW_ + pix;
    unsigned short* op = xT + ((size_t)b * HW_ + pix) * CI_;
    float f[CI_];
#pragma unroll
    for (int ci = 0; ci < CI_; ++ci) f[ci] = xp[(size_t)ci * HW_];
    union { short8 s8[4]; __hip_bfloat162 h2[16]; } u;
#pragma unroll
    for (int i = 0; i < 16; ++i)
        u.h2[i] = __float22bfloat162_rn(make_float2(f[2*i], f[2*i+1]));
#pragma unroll
    for (int i = 0; i < 4; ++i)
        *(short8*)&op[i * 8] = u.s8[i];
}

// ---------------- conv: LDS-free, barrier-free implicit GEMM ----------------
// Block: 4 oh rows (one per wave) x 64 ow x 32 co. Per wave: 8 accs, 72 MFMA,
// 36 A-loads (each a fully-coalesced 1KB wave-load from NHWC xT), 18 B-loads (L1-hot).
// A-frag: m=lane&15 (pixel), k=quad*8+j = ci  -> xT[b][oh+kh][ow+kw][quad*8..+7], 16B chunk
// C/D: col(n=co)=lane&15, row(m=pixel)=quad*4+reg (verified R2/R3)
__global__ __launch_bounds__(256) void conv_mfma(
    const unsigned short* __restrict__ xT, const unsigned short* __restrict__ wbf,
    const float* __restrict__ bias, float* __restrict__ out)
{
    const int t    = threadIdx.x;
    const int lane = t & 63;
    const int wv   = t >> 6;
    const int i16  = lane & 15;
    const int quad = lane >> 4;
    const int ow0  = blockIdx.x * 64;
    const int oh   = blockIdx.y * 4 + wv;
    const int b    = blockIdx.z;
    if (oh >= OH_) return;            // no barriers in this kernel -> safe early exit

    // Per-ot lane offset within a row: clamped pixel*32 + quad*8 (elements).
    // Clamp keeps edge-tile loads in-bounds; clamped lanes' outputs are discarded.
    int aoff[4];
#pragma unroll
    for (int ot = 0; ot < 4; ++ot) {
        int px = ow0 + ot * 16 + i16;
        if (px > OW_ - 1) px = OW_ - 1;       // px+kw <= 223 stays in-row
        aoff[ot] = px * CI_ + quad * 8;
    }
    const unsigned short* xb  = xT + (size_t)b * HW_ * CI_;
    const unsigned short* wr0 = wbf + (size_t)i16 * K_;          // co = i16
    const unsigned short* wr1 = wbf + (size_t)(16 + i16) * K_;   // co = 16+i16

    float4v acc[4][2] = {};

#pragma unroll
    for (int g = 0; g < 9; ++g) {
        const int kh = g / 3;
        const int kw = g - kh * 3;
        const short8 b0 = *(const short8*)&wr0[g * 32 + quad * 8];
        const short8 b1 = *(const short8*)&wr1[g * 32 + quad * 8];
        const unsigned short* rbase = xb + (size_t)(oh + kh) * ROWSTR + kw * CI_;
#pragma unroll
        for (int ot = 0; ot < 4; ++ot) {
            const short8 a = *(const short8*)&rbase[aoff[ot]];
            acc[ot][0] = __builtin_amdgcn_mfma_f32_16x16x32_bf16(a, b0, acc[ot][0], 0, 0, 0);
            acc[ot][1] = __builtin_amdgcn_mfma_f32_16x16x32_bf16(a, b1, acc[ot][1], 0, 0, 0);
        }
    }

    // Epilogue: per (ot,half) one dwordx4 store -> 4 quads give 64B-contiguous
    // runs per co-plane per instruction (dense sectors, no write amplification).
    const float bv0 = bias[i16];
    const float bv1 = bias[16 + i16];
    const size_t o0 = ((size_t)(b * CO_ + i16) * OH_ + oh) * (size_t)OW_;
    const size_t o1 = ((size_t)(b * CO_ + 16 + i16) * OH_ + oh) * (size_t)OW_;
#pragma unroll
    for (int ot = 0; ot < 4; ++ot) {
        const int owq = ow0 + ot * 16 + quad * 4;
        float4u v0 = { acc[ot][0][0] + bv0, acc[ot][0][1] + bv0,
                       acc[ot][0][2] + bv0, acc[ot][0][3] + bv0 };
        float4u v1 = { acc[ot][1][0] + bv1, acc[ot][1][1] + bv1,
                       acc[ot][1][2] + bv1, acc[ot][1][3] + bv1 };
        if (owq + 3 < OW_) {
            *(float4u*)&out[o0 + owq] = v0;
            *(float4u*)&out[o1 + owq] = v1;
        } else {
#pragma unroll
            for (int r = 0; r < 4; ++r) {
                if (owq + r < OW_) {
                    out[o0 + owq + r] = acc[ot][0][r] + bv0;
                    out[o1 + owq + r] = acc[ot][1][r] + bv1;
                }
            }
        }
    }
}

// ---------------- fallback (R2 structure) if ws can't hold xT ----------------
#define XCOLS 66
#define CISTR 40
__global__ __launch_bounds__(256) void conv_fb(
    const float* __restrict__ x, const unsigned short* __restrict__ wbf,
    const float* __restrict__ bias, float* __restrict__ out)
{
    __shared__ unsigned short Xs[3 * XCOLS * CISTR];
    const int t    = threadIdx.x;
    const int lane = t & 63;
    const int wv   = t >> 6;
    const int ow0  = blockIdx.x * 64;
    const int oh   = blockIdx.y;
    const int b    = blockIdx.z;
    {
        const int col = t & 63;
        const int ci0 = (t >> 6) * 8;
        const float* xb = x + (size_t)b * CI_ * HW_;
#pragma unroll
        for (int kh = 0; kh < 3; ++kh) {
            const float* base = xb + (size_t)(oh + kh) * W_ + ow0;
            for (int rep = 0; rep < 2; ++rep) {
                const int c2 = rep == 0 ? col : 64 + col;
                if (rep == 1 && col >= 2) break;
                const bool v = (ow0 + c2) < W_;
                float f[8];
#pragma unroll
                for (int i = 0; i < 8; ++i)
                    f[i] = v ? base[(size_t)(ci0 + i) * HW_ + c2] : 0.0f;
                union { short8 s8; __hip_bfloat162 h2[4]; } u;
#pragma unroll
                for (int i = 0; i < 4; ++i)
                    u.h2[i] = __float22bfloat162_rn(make_float2(f[2*i], f[2*i+1]));
                *(short8*)&Xs[(kh * XCOLS + c2) * CISTR + ci0] = u.s8;
            }
        }
    }
    __syncthreads();
    const int i16  = lane & 15;
    const int quad = lane >> 4;
    float4v acc0 = {0.f,0.f,0.f,0.f}, acc1 = {0.f,0.f,0.f,0.f};
    const unsigned short* wr0 = wbf + (size_t)i16 * K_;
    const unsigned short* wr1 = wbf + (size_t)(16 + i16) * K_;
#pragma unroll
    for (int g = 0; g < 9; ++g) {
        const int kh = g / 3, kw = g - kh * 3;
        const short8 a  = *(const short8*)&Xs[(kh * XCOLS + wv * 16 + i16 + kw) * CISTR + quad * 8];
        const short8 b0 = *(const short8*)&wr0[g * 32 + quad * 8];
        const short8 b1 = *(const short8*)&wr1[g * 32 + quad * 8];
        acc0 = __builtin_amdgcn_mfma_f32_16x16x32_bf16(a, b0, acc0, 0, 0, 0);
        acc1 = __builtin_amdgcn_mfma_f32_16x16x32_bf16(a, b1, acc1, 0, 0, 0);
    }
    const float bv0 = bias[i16], bv1 = bias[16 + i16];
    const int owbase = ow0 + wv * 16 + quad * 4;
    const size_t o0 = ((size_t)(b * CO_ + i16) * OH_ + oh) * (size_t)OW_;
    const size_t o1 = ((size_t)(b * CO_ + 16 + i16) * OH_ + oh) * (size_t)OW_;
#pragma unroll
    for (int r = 0; r < 4; ++r) {
        const int ow = owbase + r;
        if (ow < OW_) { out[o0 + ow] = acc0[r] + bv0; out[o1 + ow] = acc1[r] + bv1; }
    }
}

extern "C" void kernel_launch(void* const* d_in, const int* in_sizes, int n_in,
                              void* d_out, int out_size, void* d_ws, size_t ws_size,
                              hipStream_t stream) {
    const float* x    = (const float*)d_in[0];
    const float* w    = (const float*)d_in[1];
    const float* bias = (const float*)d_in[2];
    float* out        = (float*)d_out;
    unsigned short* wbf = (unsigned short*)d_ws;                       // 18,432 B

    wprep<<<(CO_ * K_ + 255) / 256, 256, 0, stream>>>(w, wbf);

    if (ws_size >= XT_OFF + XT_BYTES) {
        unsigned short* xT = (unsigned short*)((char*)d_ws + XT_OFF);
        xform<<<dim3(HW_ / 256, B_), 256, 0, stream>>>(x, xT);         // 196 x 16
        dim3 grid((OW_ + 63) / 64, (OH_ + 3) / 4, B_);                 // 4 x 56 x 16
        conv_mfma<<<grid, 256, 0, stream>>>(xT, wbf, bias, out);
    } else {
        dim3 grid((OW_ + 63) / 64, OH_, B_);
        conv_fb<<<grid, 256, 0, stream>>>(x, wbf, bias, out);
    }
}